// Round 1
// baseline (851.209 us; speedup 1.0000x reference)
//
#include <hip/hip_runtime.h>
#include <stdint.h>
#include <stddef.h>

typedef short s16;
typedef __attribute__((ext_vector_type(8))) short short8;
typedef __attribute__((ext_vector_type(4))) float floatx4;

__device__ __forceinline__ float bf2f(short s) {
    union { float f; uint32_t u; } c; c.u = ((uint32_t)(uint16_t)s) << 16; return c.f;
}
__device__ __forceinline__ short f2bf(float f) {
    union { float f; uint32_t u; } c; c.f = f;
    uint32_t u = c.u;
    u += 0x7fffu + ((u >> 16) & 1u);   // RNE
    return (short)(u >> 16);
}

// ---------------- K_cvt: x fp32 -> bf16 (8 elem / thread) ----------------
__global__ __launch_bounds__(256) void cvt_kernel(const float* __restrict__ src,
                                                  s16* __restrict__ dst) {
    size_t i = (size_t)blockIdx.x * 256 + threadIdx.x;
    const floatx4* s4 = (const floatx4*)src;
    floatx4 a = s4[i * 2], b = s4[i * 2 + 1];
    short8 o;
    o[0] = f2bf(a[0]); o[1] = f2bf(a[1]); o[2] = f2bf(a[2]); o[3] = f2bf(a[3]);
    o[4] = f2bf(b[0]); o[5] = f2bf(b[1]); o[6] = f2bf(b[2]); o[7] = f2bf(b[3]);
    ((short8*)dst)[i] = o;
}

// ------------- K0: transpose weight fp32 (K,N) -> bf16 (N,K) -------------
__global__ __launch_bounds__(256) void transpose_kernel(const float* __restrict__ w,
                                                        s16* __restrict__ wt,
                                                        int K, int N) {
    int idx = blockIdx.x * 256 + threadIdx.x;
    if (idx >= K * N) return;
    int n = idx / K, k = idx - n * K;      // wt[n][k] = w[k][n]; writes coalesced
    wt[idx] = f2bf(w[(size_t)k * N + n]);
}

// row m (0..100351) -> pointer to its 512-ch row inside x (window gather)
__device__ __forceinline__ const s16* x_row_ptr(const s16* xb, int m) {
    int win = m / 49, t = m - win * 49;
    int b = win >> 6, rem = win & 63, hb = rem >> 3, wb = rem & 7;
    int r = t / 7, c = t - r * 7;
    int n = (hb * 7 + r) * 56 + wb * 7 + c;
    return xb + ((size_t)b * 3136 + n) * 512;
}

// ------------- GEMM: 128x128 tile, BK=64, 16x16x32 bf16 MFMA -------------
// MODE 0: A = xbf (window-gathered rows), N=1536, out = qkv bf16 (m,1536)
// MODE 1: A = attn bf16 (contiguous rows), N=512, out = d_out fp32 (window-scattered)
template <int MODE>
__global__ __launch_bounds__(256) void gemm_kernel(const s16* __restrict__ A,
                                                   const s16* __restrict__ Bt,
                                                   const float* __restrict__ bias,
                                                   void* __restrict__ outp) {
    constexpr int NT = (MODE == 0) ? 12 : 4;
    const int tm = blockIdx.x / NT, tn = blockIdx.x % NT;
    const int tid = threadIdx.x, wave = tid >> 6, lane = tid & 63;

    __shared__ s16 lA[128 * 64];   // row-major (m, k)
    __shared__ s16 lB[128 * 64];   // row-major (n, k)  (Bt is N-major)

    const int sub  = lane >> 3;            // row within 8-row chunk
    const int col8 = (lane & 7) << 3;      // k offset (8 elems = 16B)
    const s16* a_src[4];
    const s16* b_src[4];
#pragma unroll
    for (int i = 0; i < 4; ++i) {
        int ch = wave * 4 + i;             // chunk 0..15 (1 KiB each)
        int row = ch * 8 + sub;            // 0..127
        if (MODE == 0) a_src[i] = x_row_ptr(A, tm * 128 + row) + col8;
        else           a_src[i] = A + (size_t)(tm * 128 + row) * 512 + col8;
        b_src[i] = Bt + (size_t)(tn * 128 + row) * 512 + col8;
    }

    floatx4 acc[4][4];
#pragma unroll
    for (int mt = 0; mt < 4; ++mt)
#pragma unroll
        for (int nt = 0; nt < 4; ++nt)
            acc[mt][nt] = (floatx4){0.f, 0.f, 0.f, 0.f};

    const int wm = wave >> 1, wn = wave & 1;
    const int lm = lane & 15, quad = lane >> 4;

    for (int kt = 0; kt < 8; ++kt) {
#pragma unroll
        for (int i = 0; i < 4; ++i) {
            int ch = wave * 4 + i;
            __builtin_amdgcn_global_load_lds(
                (const __attribute__((address_space(1))) void*)a_src[i],
                (__attribute__((address_space(3))) void*)&lA[ch * 512], 16, 0, 0);
            __builtin_amdgcn_global_load_lds(
                (const __attribute__((address_space(1))) void*)b_src[i],
                (__attribute__((address_space(3))) void*)&lB[ch * 512], 16, 0, 0);
            a_src[i] += 64;
            b_src[i] += 64;
        }
        __syncthreads();
#pragma unroll
        for (int kb = 0; kb < 2; ++kb) {
            const int krd = kb * 32 + quad * 8;
            short8 af[4], bq[4];
#pragma unroll
            for (int mt = 0; mt < 4; ++mt)
                af[mt] = *(const short8*)&lA[(wm * 64 + mt * 16 + lm) * 64 + krd];
#pragma unroll
            for (int nt = 0; nt < 4; ++nt)
                bq[nt] = *(const short8*)&lB[(wn * 64 + nt * 16 + lm) * 64 + krd];
#pragma unroll
            for (int mt = 0; mt < 4; ++mt)
#pragma unroll
                for (int nt = 0; nt < 4; ++nt)
                    acc[mt][nt] = __builtin_amdgcn_mfma_f32_16x16x32_bf16(
                        af[mt], bq[nt], acc[mt][nt], 0, 0, 0);
        }
        __syncthreads();
    }

    // ---- epilogue: C/D layout col = lane&15, row = quad*4 + reg ----
    float bv[4];
#pragma unroll
    for (int nt = 0; nt < 4; ++nt)
        bv[nt] = bias[tn * 128 + wn * 64 + nt * 16 + lm];

#pragma unroll
    for (int mt = 0; mt < 4; ++mt) {
        int mbase = tm * 128 + wm * 64 + mt * 16 + quad * 4;
#pragma unroll
        for (int i = 0; i < 4; ++i) {
            int m = mbase + i;
            size_t rowoff;
            if (MODE == 1) {
                int win = m / 49, t = m - win * 49;
                int b = win >> 6, rem = win & 63, hb = rem >> 3, wb = rem & 7;
                int r = t / 7, c = t - r * 7;
                int n = (hb * 7 + r) * 56 + wb * 7 + c;
                rowoff = ((size_t)b * 3136 + n) * 512;
            } else {
                rowoff = (size_t)m * 1536;
            }
#pragma unroll
            for (int nt = 0; nt < 4; ++nt) {
                int coln = tn * 128 + wn * 64 + nt * 16 + lm;
                float v = acc[mt][nt][i] + bv[nt];
                if (MODE == 0) ((s16*)outp)[rowoff + coln] = f2bf(v);
                else           ((float*)outp)[rowoff + coln] = v;
            }
        }
    }
}

// --------- K2: per-(win,token) 8x8 head attention; 1 wave / row ----------
// qkv row m: [0,512)=q (h*64+d), [512,1024)=k, [1024,1536)=v
// out layout: attn[win*25088 + h*3136 + t*64 + d]  (== (m,512) rows for proj)
__global__ __launch_bounds__(256) void attn_kernel(const s16* __restrict__ qkv,
                                                   s16* __restrict__ attn) {
    const int tid = threadIdx.x, wave = tid >> 6, lane = tid & 63;
    const int m = blockIdx.x * 4 + wave;   // grid 25088 * 4 = 100352 exact

    __shared__ s16 sh[4][1536];
    s16* my = sh[wave];
    const s16* row = qkv + (size_t)m * 1536;
#pragma unroll
    for (int i = 0; i < 3; ++i)
        *(short8*)&my[i * 512 + lane * 8] = *(const short8*)&row[i * 512 + lane * 8];
    __syncthreads();

    const int h = lane >> 3, g = lane & 7;
    const s16* qs = my + h * 64;
    const s16* ks = my + 512 + g * 64;
    const s16* vs = my + 1024;

    // S[h][g] = (q_h . k_g) / 8 ; d-rotation by h avoids LDS bank conflicts
    float s = 0.f;
#pragma unroll
    for (int db = 0; db < 8; ++db) {
        int d0 = ((db + h) & 7) * 8;
        short8 q8 = *(const short8*)&qs[d0];
        short8 k8 = *(const short8*)&ks[d0];
#pragma unroll
        for (int j = 0; j < 8; ++j) s += bf2f(q8[j]) * bf2f(k8[j]);
    }
    s *= 0.125f;

    // softmax over g within each 8-lane group
    float mx = s;
    mx = fmaxf(mx, __shfl_xor(mx, 1));
    mx = fmaxf(mx, __shfl_xor(mx, 2));
    mx = fmaxf(mx, __shfl_xor(mx, 4));
    float p = __expf(s - mx);
    float sum = p;
    sum += __shfl_xor(sum, 1);
    sum += __shfl_xor(sum, 2);
    sum += __shfl_xor(sum, 4);
    p /= sum;

    // O[h][d0..d0+7], d0 = (lane&7)*8 ; p[h][gg] lives in lane h*8+gg
    float o[8];
#pragma unroll
    for (int j = 0; j < 8; ++j) o[j] = 0.f;
    const int dgrp = (lane & 7) * 8;
#pragma unroll
    for (int gg = 0; gg < 8; ++gg) {
        float pg = __shfl(p, h * 8 + gg);
        short8 v8 = *(const short8*)&vs[gg * 64 + dgrp];
#pragma unroll
        for (int j = 0; j < 8; ++j) o[j] += pg * bf2f(v8[j]);
    }

    int win = m / 49, t = m - win * 49;
    s16* dst = attn + (size_t)win * 25088 + h * 3136 + t * 64 + dgrp;
    short8 ob;
#pragma unroll
    for (int j = 0; j < 8; ++j) ob[j] = f2bf(o[j]);
    *(short8*)dst = ob;
}

extern "C" void kernel_launch(void* const* d_in, const int* in_sizes, int n_in,
                              void* d_out, int out_size, void* d_ws, size_t ws_size,
                              hipStream_t stream) {
    const float* x      = (const float*)d_in[0];
    const float* w_qkv  = (const float*)d_in[1];
    const float* b_qkv  = (const float*)d_in[2];
    const float* w_proj = (const float*)d_in[3];
    const float* b_proj = (const float*)d_in[4];

    char* ws = (char*)d_ws;
    // 102,760,448 B = 100352*512*2 ; 308,281,344 B = 100352*1536*2
    s16* xbf    = (s16*)ws;
    s16* qkv    = (s16*)(ws + 102760448ull);
    s16* attn   = (s16*)(ws + 102760448ull + 308281344ull);
    s16* wqkvT  = (s16*)(ws + 102760448ull + 308281344ull + 102760448ull);
    s16* wprojT = (s16*)(ws + 102760448ull + 308281344ull + 102760448ull + 1572864ull);

    cvt_kernel<<<25088, 256, 0, stream>>>(x, xbf);                       // 51.4M elems
    transpose_kernel<<<3072, 256, 0, stream>>>(w_qkv, wqkvT, 512, 1536);
    transpose_kernel<<<1024, 256, 0, stream>>>(w_proj, wprojT, 512, 512);
    gemm_kernel<0><<<784 * 12, 256, 0, stream>>>(xbf, wqkvT, b_qkv, qkv);
    attn_kernel<<<25088, 256, 0, stream>>>(qkv, attn);
    gemm_kernel<1><<<784 * 4, 256, 0, stream>>>(attn, wprojT, b_proj, d_out);
}

// Round 2
// 814.061 us; speedup vs baseline: 1.0456x; 1.0456x over previous
//
#include <hip/hip_runtime.h>
#include <stdint.h>
#include <stddef.h>

typedef short s16;
typedef __attribute__((ext_vector_type(8))) short short8;
typedef __attribute__((ext_vector_type(4))) float floatx4;

__device__ __forceinline__ float bf2f(short s) {
    union { float f; uint32_t u; } c; c.u = ((uint32_t)(uint16_t)s) << 16; return c.f;
}
__device__ __forceinline__ short f2bf(float f) {
    union { float f; uint32_t u; } c; c.f = f;
    uint32_t u = c.u;
    u += 0x7fffu + ((u >> 16) & 1u);   // RNE
    return (short)(u >> 16);
}

// ---------------- K_cvt: x fp32 -> bf16 (8 elem / thread) ----------------
__global__ __launch_bounds__(256) void cvt_kernel(const float* __restrict__ src,
                                                  s16* __restrict__ dst) {
    size_t i = (size_t)blockIdx.x * 256 + threadIdx.x;
    const floatx4* s4 = (const floatx4*)src;
    floatx4 a = s4[i * 2], b = s4[i * 2 + 1];
    short8 o;
    o[0] = f2bf(a[0]); o[1] = f2bf(a[1]); o[2] = f2bf(a[2]); o[3] = f2bf(a[3]);
    o[4] = f2bf(b[0]); o[5] = f2bf(b[1]); o[6] = f2bf(b[2]); o[7] = f2bf(b[3]);
    ((short8*)dst)[i] = o;
}

// ------------- K0: transpose weight fp32 (K,N) -> bf16 (N,K) -------------
__global__ __launch_bounds__(256) void transpose_kernel(const float* __restrict__ w,
                                                        s16* __restrict__ wt,
                                                        int K, int N) {
    int idx = blockIdx.x * 256 + threadIdx.x;
    if (idx >= K * N) return;
    int n = idx / K, k = idx - n * K;      // wt[n][k] = w[k][n]; writes coalesced
    wt[idx] = f2bf(w[(size_t)k * N + n]);
}

// row m (0..100351) -> pointer to its 512-ch row inside x (window gather)
__device__ __forceinline__ const s16* x_row_ptr(const s16* xb, int m) {
    int win = m / 49, t = m - win * 49;
    int b = win >> 6, rem = win & 63, hb = rem >> 3, wb = rem & 7;
    int r = t / 7, c = t - r * 7;
    int n = (hb * 7 + r) * 56 + wb * 7 + c;
    return xb + ((size_t)b * 3136 + n) * 512;
}

// ------------- GEMM: 128x128 tile, BK=64, 16x16x32 bf16 MFMA -------------
// LDS layout is XOR-swizzled: slot (row, c) holds global k-block (c ^ (row&7)).
// Reader lane lm (rows differing in low 3 bits) then hits 8 distinct 16B bank
// slots -> 2 lanes/slot = conflict-free (G4/m136). global_load_lds stays
// contiguous (lane*16B) because the swizzle permutes the SOURCE column only.
// MODE 0: A = xbf (window-gathered rows), N=1536, out = qkv bf16 (m,1536)
// MODE 1: A = attn bf16 (contiguous rows), N=512, out = d_out fp32 (window-scattered)
template <int MODE>
__global__ __launch_bounds__(256) void gemm_kernel(const s16* __restrict__ A,
                                                   const s16* __restrict__ Bt,
                                                   const float* __restrict__ bias,
                                                   void* __restrict__ outp) {
    constexpr int NT = (MODE == 0) ? 12 : 4;
    const int tm = blockIdx.x / NT, tn = blockIdx.x % NT;
    const int tid = threadIdx.x, wave = tid >> 6, lane = tid & 63;

    __shared__ s16 lA[128 * 64];   // (m, k) xor-swizzled
    __shared__ s16 lB[128 * 64];   // (n, k) xor-swizzled

    const int sub  = lane >> 3;                    // row within 8-row chunk
    const int col8 = (((lane & 7) ^ sub) << 3);    // swizzled source k-block
    const s16* a_src[4];
    const s16* b_src[4];
#pragma unroll
    for (int i = 0; i < 4; ++i) {
        int ch = wave * 4 + i;             // chunk 0..15 (1 KiB each)
        int row = ch * 8 + sub;            // 0..127
        if (MODE == 0) a_src[i] = x_row_ptr(A, tm * 128 + row) + col8;
        else           a_src[i] = A + (size_t)(tm * 128 + row) * 512 + col8;
        b_src[i] = Bt + (size_t)(tn * 128 + row) * 512 + col8;
    }

    floatx4 acc[4][4];
#pragma unroll
    for (int mt = 0; mt < 4; ++mt)
#pragma unroll
        for (int nt = 0; nt < 4; ++nt)
            acc[mt][nt] = (floatx4){0.f, 0.f, 0.f, 0.f};

    const int wm = wave >> 1, wn = wave & 1;
    const int lm = lane & 15, quad = lane >> 4;

    for (int kt = 0; kt < 8; ++kt) {
#pragma unroll
        for (int i = 0; i < 4; ++i) {
            int ch = wave * 4 + i;
            __builtin_amdgcn_global_load_lds(
                (const __attribute__((address_space(1))) void*)a_src[i],
                (__attribute__((address_space(3))) void*)&lA[ch * 512], 16, 0, 0);
            __builtin_amdgcn_global_load_lds(
                (const __attribute__((address_space(1))) void*)b_src[i],
                (__attribute__((address_space(3))) void*)&lB[ch * 512], 16, 0, 0);
            a_src[i] += 64;
            b_src[i] += 64;
        }
        __syncthreads();
#pragma unroll
        for (int kb = 0; kb < 2; ++kb) {
            const int cb = kb * 4 + quad;              // k-block 0..7
            const int sw = (cb ^ (lm & 7)) << 3;       // swizzled LDS k offset
            short8 af[4], bq[4];
#pragma unroll
            for (int mt = 0; mt < 4; ++mt)
                af[mt] = *(const short8*)&lA[(wm * 64 + mt * 16 + lm) * 64 + sw];
#pragma unroll
            for (int nt = 0; nt < 4; ++nt)
                bq[nt] = *(const short8*)&lB[(wn * 64 + nt * 16 + lm) * 64 + sw];
#pragma unroll
            for (int mt = 0; mt < 4; ++mt)
#pragma unroll
                for (int nt = 0; nt < 4; ++nt)
                    acc[mt][nt] = __builtin_amdgcn_mfma_f32_16x16x32_bf16(
                        af[mt], bq[nt], acc[mt][nt], 0, 0, 0);
        }
        __syncthreads();
    }

    // ---- epilogue: C/D layout col = lane&15, row = quad*4 + reg ----
    float bv[4];
#pragma unroll
    for (int nt = 0; nt < 4; ++nt)
        bv[nt] = bias[tn * 128 + wn * 64 + nt * 16 + lm];

#pragma unroll
    for (int mt = 0; mt < 4; ++mt) {
        int mbase = tm * 128 + wm * 64 + mt * 16 + quad * 4;
#pragma unroll
        for (int i = 0; i < 4; ++i) {
            int m = mbase + i;
            size_t rowoff;
            if (MODE == 1) {
                int win = m / 49, t = m - win * 49;
                int b = win >> 6, rem = win & 63, hb = rem >> 3, wb = rem & 7;
                int r = t / 7, c = t - r * 7;
                int n = (hb * 7 + r) * 56 + wb * 7 + c;
                rowoff = ((size_t)b * 3136 + n) * 512;
            } else {
                rowoff = (size_t)m * 1536;
            }
#pragma unroll
            for (int nt = 0; nt < 4; ++nt) {
                int coln = tn * 128 + wn * 64 + nt * 16 + lm;
                float v = acc[mt][nt][i] + bv[nt];
                if (MODE == 0) ((s16*)outp)[rowoff + coln] = f2bf(v);
                else           ((float*)outp)[rowoff + coln] = v;
            }
        }
    }
}

// --------- K2: per-(win,token) 8x8 head attention; 1 wave / row ----------
// qkv row m: [0,512)=q (h*64+d), [512,1024)=k, [1024,1536)=v
// out layout: attn[win*25088 + h*3136 + t*64 + d]  (== (m,512) rows for proj)
__global__ __launch_bounds__(256) void attn_kernel(const s16* __restrict__ qkv,
                                                   s16* __restrict__ attn) {
    const int tid = threadIdx.x, wave = tid >> 6, lane = tid & 63;
    const int m = blockIdx.x * 4 + wave;   // grid 25088 * 4 = 100352 exact

    __shared__ s16 sh[4][1536];
    s16* my = sh[wave];
    const s16* row = qkv + (size_t)m * 1536;
#pragma unroll
    for (int i = 0; i < 3; ++i)
        *(short8*)&my[i * 512 + lane * 8] = *(const short8*)&row[i * 512 + lane * 8];
    __syncthreads();

    const int h = lane >> 3, g = lane & 7;
    const s16* qs = my + h * 64;
    const s16* ks = my + 512 + g * 64;
    const s16* vs = my + 1024;

    // S[h][g] = (q_h . k_g) / 8 ; d-rotation by h avoids LDS bank conflicts
    float s = 0.f;
#pragma unroll
    for (int db = 0; db < 8; ++db) {
        int d0 = ((db + h) & 7) * 8;
        short8 q8 = *(const short8*)&qs[d0];
        short8 k8 = *(const short8*)&ks[d0];
#pragma unroll
        for (int j = 0; j < 8; ++j) s += bf2f(q8[j]) * bf2f(k8[j]);
    }
    s *= 0.125f;

    // softmax over g within each 8-lane group
    float mx = s;
    mx = fmaxf(mx, __shfl_xor(mx, 1));
    mx = fmaxf(mx, __shfl_xor(mx, 2));
    mx = fmaxf(mx, __shfl_xor(mx, 4));
    float p = __expf(s - mx);
    float sum = p;
    sum += __shfl_xor(sum, 1);
    sum += __shfl_xor(sum, 2);
    sum += __shfl_xor(sum, 4);
    p /= sum;

    // O[h][d0..d0+7], d0 = (lane&7)*8 ; p[h][gg] lives in lane h*8+gg
    float o[8];
#pragma unroll
    for (int j = 0; j < 8; ++j) o[j] = 0.f;
    const int dgrp = (lane & 7) * 8;
#pragma unroll
    for (int gg = 0; gg < 8; ++gg) {
        float pg = __shfl(p, h * 8 + gg);
        short8 v8 = *(const short8*)&vs[gg * 64 + dgrp];
#pragma unroll
        for (int j = 0; j < 8; ++j) o[j] += pg * bf2f(v8[j]);
    }

    int win = m / 49, t = m - win * 49;
    s16* dst = attn + (size_t)win * 25088 + h * 3136 + t * 64 + dgrp;
    short8 ob;
#pragma unroll
    for (int j = 0; j < 8; ++j) ob[j] = f2bf(o[j]);
    *(short8*)dst = ob;
}

extern "C" void kernel_launch(void* const* d_in, const int* in_sizes, int n_in,
                              void* d_out, int out_size, void* d_ws, size_t ws_size,
                              hipStream_t stream) {
    const float* x      = (const float*)d_in[0];
    const float* w_qkv  = (const float*)d_in[1];
    const float* b_qkv  = (const float*)d_in[2];
    const float* w_proj = (const float*)d_in[3];
    const float* b_proj = (const float*)d_in[4];

    char* ws = (char*)d_ws;
    // 102,760,448 B = 100352*512*2 ; 308,281,344 B = 100352*1536*2
    s16* xbf    = (s16*)ws;
    s16* qkv    = (s16*)(ws + 102760448ull);
    s16* attn   = (s16*)(ws + 102760448ull + 308281344ull);
    s16* wqkvT  = (s16*)(ws + 102760448ull + 308281344ull + 102760448ull);
    s16* wprojT = (s16*)(ws + 102760448ull + 308281344ull + 102760448ull + 1572864ull);

    cvt_kernel<<<25088, 256, 0, stream>>>(x, xbf);                       // 51.4M elems
    transpose_kernel<<<3072, 256, 0, stream>>>(w_qkv, wqkvT, 512, 1536);
    transpose_kernel<<<1024, 256, 0, stream>>>(w_proj, wprojT, 512, 512);
    gemm_kernel<0><<<784 * 12, 256, 0, stream>>>(xbf, wqkvT, b_qkv, qkv);
    attn_kernel<<<25088, 256, 0, stream>>>(qkv, attn);
    gemm_kernel<1><<<784 * 4, 256, 0, stream>>>(attn, wprojT, b_proj, d_out);
}